// Round 1
// baseline (6965.483 us; speedup 1.0000x reference)
//
#include <hip/hip_runtime.h>
#include <math.h>

#define NSTAGES 8
#define NCODES  1024
#define DIM     256
#define NROWS   131072
#define TM      64          // rows per block
#define RES_STRIDE 260      // 256 + 4 pad (keeps 16B alignment, breaks bank aliasing)
#define KSL     8           // K slice depth staged in LDS
#define EPSV    1e-12f

// monotonic unsigned key for float ordering
__device__ __forceinline__ unsigned int fkey(float f) {
    unsigned int u = __float_as_uint(f);
    return (u & 0x80000000u) ? ~u : (u | 0x80000000u);
}

// ---------------- prep: transpose codebooks + code norms ----------------
// grid: 8 stages * 16 code-chunks of 64 codes; block 256
__global__ __launch_bounds__(256) void prep_kernel(const float* __restrict__ cb,
                                                   float* __restrict__ cbT,
                                                   float* __restrict__ cn) {
    __shared__ float tile[64][RES_STRIDE];
    __shared__ float pr[256];
    int s  = blockIdx.x >> 4;
    int c0 = (blockIdx.x & 15) * 64;
    int t  = threadIdx.x;
    const float* src = cb + ((size_t)s * NCODES + c0) * DIM;
#pragma unroll
    for (int i = 0; i < 16; ++i) {
        int e4 = t + 256 * i;           // 4096 float4s = 64 codes x 256 dims
        int c  = e4 >> 6;
        int d4 = (e4 & 63) * 4;
        *(float4*)&tile[c][d4] = ((const float4*)src)[e4];
    }
    __syncthreads();
    // code norms (fp32)
    {
        int c = t >> 2, q = t & 3;
        float sum = 0.f;
#pragma unroll 16
        for (int d = q * 64; d < q * 64 + 64; ++d) { float x = tile[c][d]; sum += x * x; }
        pr[t] = sum;
    }
    __syncthreads();
    if (t < 64) cn[(size_t)s * NCODES + c0 + t] = pr[4*t] + pr[4*t+1] + pr[4*t+2] + pr[4*t+3];
    // transposed write: cbT[(s*256 + k)*1024 + c]
#pragma unroll
    for (int i = 0; i < 16; ++i) {
        int e4 = t + 256 * i;           // over [k:256][c4:16]
        int k  = e4 >> 4;
        int c4 = (e4 & 15) * 4;
        float4 v = make_float4(tile[c4+0][k], tile[c4+1][k], tile[c4+2][k], tile[c4+3][k]);
        *(float4*)&cbT[(size_t)(s * DIM + k) * NCODES + c0 + c4] = v;
    }
}

// ---------------- init used tail of d_out ----------------
__global__ void init_used_kernel(const int* __restrict__ cbu, float* __restrict__ used) {
    int i = blockIdx.x * 256 + threadIdx.x;
    if (i < NSTAGES * NCODES) used[i] = (float)cbu[i];
}

// ---------------- main fused RVQ ----------------
// block 256 threads = 8 row-groups x 32 code-groups; 64 rows/block, all 8 stages fused
__global__ __launch_bounds__(256, 2) void rvq_kernel(const float* __restrict__ input,
                                                     const float* __restrict__ cb,
                                                     const float* __restrict__ cbT,
                                                     const float* __restrict__ cn,
                                                     const float* __restrict__ noise,
                                                     const int* __restrict__ cbu,
                                                     const int* __restrict__ tmp,
                                                     float* __restrict__ out,
                                                     float* __restrict__ used) {
    __shared__ float res[TM][RES_STRIDE];          // 66560 B
    __shared__ float Bs[KSL][256];                 // 8192 B
    __shared__ unsigned long long bestkey[TM];     // 512 B
    __shared__ float pr[256];
    __shared__ float pn[256];
    __shared__ float scl[TM];

    int t = threadIdx.x;
    int row0 = blockIdx.x * TM;
    const float* inp = input + (size_t)row0 * DIM;

    // load residual tile (coalesced)
#pragma unroll
    for (int i = 0; i < 16; ++i) {
        int e4 = t + 256 * i;
        int r  = e4 >> 6;
        int d4 = (e4 & 63) * 4;
        *(float4*)&res[r][d4] = ((const float4*)inp)[e4];
    }
    if (t < TM) bestkey[t] = ~0ULL;

    int tc = t & 31;   // code group: codes tc*4 and 128+tc*4 within chunk
    int tr = t >> 5;   // row group: rows tr*4.. and 32+tr*4..

#pragma unroll 1
    for (int s = 0; s < NSTAGES; ++s) {
        unsigned long long bestr[8];
#pragma unroll
        for (int r = 0; r < 8; ++r) bestr[r] = ~0ULL;

#pragma unroll 1
        for (int cc = 0; cc < 4; ++cc) {           // code chunks of 256
            float acc[8][8];
#pragma unroll
            for (int r = 0; r < 8; ++r)
#pragma unroll
                for (int c = 0; c < 8; ++c) acc[r][c] = 0.f;

#pragma unroll 1
            for (int ks = 0; ks < DIM / KSL; ++ks) {
                __syncthreads();
                {   // stage B slice: cbT[s][ks*8 .. +7][cc*256 .. +255]
                    const float* bsrc = cbT + (size_t)(s * DIM + ks * KSL) * NCODES + cc * 256;
#pragma unroll
                    for (int j = 0; j < 2; ++j) {
                        int e4 = t + 256 * j;      // 512 float4s
                        int k  = e4 >> 6;
                        int c4 = (e4 & 63) * 4;
                        *(float4*)&Bs[k][c4] = *(const float4*)&bsrc[(size_t)k * NCODES + c4];
                    }
                }
                __syncthreads();
                int kb = ks * KSL;
#pragma unroll
                for (int kq = 0; kq < 2; ++kq) {
                    float a[8][4];
#pragma unroll
                    for (int rr = 0; rr < 4; ++rr) {
                        *(float4*)a[rr]     = *(const float4*)&res[tr*4 + rr][kb + kq*4];
                        *(float4*)a[rr + 4] = *(const float4*)&res[32 + tr*4 + rr][kb + kq*4];
                    }
                    float b[4][8];
#pragma unroll
                    for (int j = 0; j < 4; ++j) {
                        *(float4*)&b[j][0] = *(const float4*)&Bs[kq*4 + j][tc*4];
                        *(float4*)&b[j][4] = *(const float4*)&Bs[kq*4 + j][128 + tc*4];
                    }
#pragma unroll
                    for (int j = 0; j < 4; ++j)
#pragma unroll
                        for (int r = 0; r < 8; ++r)
#pragma unroll
                            for (int c = 0; c < 8; ++c)
                                acc[r][c] = fmaf(a[r][j], b[j][c], acc[r][c]);
                }
            }
            // scores + per-thread running argmin (ascending code order for tie-break)
            const float* cns = cn + (size_t)s * NCODES + cc * 256;
#pragma unroll
            for (int r = 0; r < 8; ++r) {
#pragma unroll
                for (int c = 0; c < 8; ++c) {
                    int code = (c < 4) ? (tc*4 + c) : (128 + tc*4 + (c - 4));
                    float sc = cns[code] - 2.0f * acc[r][c];
                    unsigned long long key =
                        ((unsigned long long)fkey(sc) << 32) | (unsigned int)(cc * 256 + code);
                    if (key < bestr[r]) bestr[r] = key;
                }
            }
        }
        // block-level argmin per row
#pragma unroll
        for (int r = 0; r < 8; ++r) {
            int row = (r < 4) ? (tr*4 + r) : (32 + tr*4 + (r - 4));
            atomicMin(&bestkey[row], bestr[r]);
        }
        __syncthreads();
        // residual update + used mark
        {
            int rr = t >> 2, seg = t & 3;
            int idx = (int)(bestkey[rr] & 0xFFFFFFFFu);
            const float4* cv = (const float4*)(cb + ((size_t)s * NCODES + idx) * DIM + seg * 64);
            float4* rp = (float4*)&res[rr][seg * 64];
#pragma unroll
            for (int i = 0; i < 16; ++i) {
                float4 c4 = cv[i];
                float4 rv = rp[i];
                rv.x -= c4.x; rv.y -= c4.y; rv.z -= c4.z; rv.w -= c4.w;
                rp[i] = rv;
            }
            if (t < TM) {
                int gi = s * NCODES + (int)(bestkey[t] & 0xFFFFFFFFu);
                used[gi] = (float)cbu[gi] + 1.0f;
            }
        }
        __syncthreads();
        if (t < TM) bestkey[t] = ~0ULL;   // safe: next atomics are beyond later barriers
    }

    // epilogue: norms + output
    int tm = tmp[0];
    {
        int rr = t >> 2, q = t & 3;
        const float4* np4 = (const float4*)(noise + (size_t)(row0 + rr) * DIM + q * 64);
        float sr = 0.f, sn = 0.f;
#pragma unroll
        for (int i = 0; i < 16; ++i) {
            float4 rv = *(const float4*)&res[rr][q * 64 + i * 4];
            float4 nv = np4[i];
            sr += rv.x*rv.x + rv.y*rv.y + rv.z*rv.z + rv.w*rv.w;
            sn += nv.x*nv.x + nv.y*nv.y + nv.z*nv.z + nv.w*nv.w;
        }
        pr[t] = sr; pn[t] = sn;
    }
    __syncthreads();
    if (t < TM) {
        float rs = pr[4*t] + pr[4*t+1] + pr[4*t+2] + pr[4*t+3];
        float ns = pn[4*t] + pn[4*t+1] + pn[4*t+2] + pn[4*t+3];
        scl[t] = sqrtf(rs) / sqrtf(ns) + EPSV;
    }
    __syncthreads();
    {
        float* op = out + (size_t)row0 * DIM;
        const float4* nb = (const float4*)(noise + (size_t)row0 * DIM);
#pragma unroll
        for (int i = 0; i < 16; ++i) {
            int e4 = t + 256 * i;
            int r  = e4 >> 6;
            float4 iv = ((const float4*)inp)[e4];
            float4 ov;
            if (tm) {
                float4 nv = nb[e4];
                float sc = scl[r];
                ov.x = iv.x + sc * nv.x; ov.y = iv.y + sc * nv.y;
                ov.z = iv.z + sc * nv.z; ov.w = iv.w + sc * nv.w;
            } else {
                int d4 = (e4 & 63) * 4;
                float4 rv = *(const float4*)&res[r][d4];
                ov.x = iv.x - rv.x; ov.y = iv.y - rv.y;
                ov.z = iv.z - rv.z; ov.w = iv.w - rv.w;
            }
            ((float4*)op)[e4] = ov;
        }
    }
}

extern "C" void kernel_launch(void* const* d_in, const int* in_sizes, int n_in,
                              void* d_out, int out_size, void* d_ws, size_t ws_size,
                              hipStream_t stream) {
    const float* input = (const float*)d_in[0];
    const float* cb    = (const float*)d_in[1];
    const float* noise = (const float*)d_in[2];
    const int*   cbu   = (const int*)d_in[3];
    const int*   tm    = (const int*)d_in[4];
    float* out  = (float*)d_out;
    float* used = out + (size_t)NROWS * DIM;          // tail: 8*1024 floats
    float* cbT  = (float*)d_ws;                        // 8 MB
    float* cn   = cbT + (size_t)NSTAGES * DIM * NCODES; // 32 KB

    prep_kernel<<<NSTAGES * (NCODES / 64), 256, 0, stream>>>(cb, cbT, cn);
    init_used_kernel<<<(NSTAGES * NCODES + 255) / 256, 256, 0, stream>>>(cbu, used);
    rvq_kernel<<<NROWS / TM, 256, 0, stream>>>(input, cb, cbT, cn, noise, cbu, tm, out, used);
}

// Round 2
// 1942.645 us; speedup vs baseline: 3.5856x; 3.5856x over previous
//
#include <hip/hip_runtime.h>
#include <math.h>

#define NSTAGES 8
#define NCODES  1024
#define DIM     256
#define NROWS   131072
#define TM      64
#define EPSV    1e-12f

typedef __attribute__((ext_vector_type(8))) short bf16x8;
typedef __attribute__((ext_vector_type(4))) float f32x4;

__device__ __forceinline__ unsigned fkey(float f) {
    unsigned u = __float_as_uint(f);
    return (u & 0x80000000u) ? ~u : (u | 0x80000000u);
}
__device__ __forceinline__ short f2bf(float f) {           // RNE bf16
    unsigned u = __float_as_uint(f);
    u = u + 0x7fffu + ((u >> 16) & 1u);
    return (short)(u >> 16);
}
__device__ __forceinline__ float bf2f(short h) {
    return __uint_as_float(((unsigned)(unsigned short)h) << 16);
}

// ---------------- prep: codebooks -> B-fragment-linear bf16 split + norms ----
// grid: 8 stages * 16 chunks of 64 codes; block 256
__global__ __launch_bounds__(256) void prep_kernel(const float* __restrict__ cb,
                                                   short* __restrict__ chF,
                                                   short* __restrict__ clF,
                                                   float* __restrict__ cn) {
    __shared__ float tile[64][260];
    __shared__ float pr[256];
    int s  = blockIdx.x >> 4;
    int c0 = (blockIdx.x & 15) * 64;
    int t  = threadIdx.x;
    const float4* src = (const float4*)(cb + ((size_t)s * NCODES + c0) * DIM);
#pragma unroll
    for (int i = 0; i < 16; ++i) {
        int e4 = t + 256 * i;
        int c  = e4 >> 6;
        int d4 = (e4 & 63) * 4;
        *(float4*)&tile[c][d4] = src[e4];
    }
    __syncthreads();
    {
        int c = t >> 2, q = t & 3;
        float sum = 0.f;
#pragma unroll 16
        for (int d = q * 64; d < q * 64 + 64; ++d) { float x = tile[c][d]; sum += x * x; }
        pr[t] = sum;
    }
    __syncthreads();
    if (t < 64) cn[(size_t)s * NCODES + c0 + t] = pr[4*t] + pr[4*t+1] + pr[4*t+2] + pr[4*t+3];
    // fragment writes: B[k][n] layout, lane = (k-quad)*16 + n_local, 8 bf16/lane
#pragma unroll
    for (int i = 0; i < 8; ++i) {
        int fi   = t + 256 * i;          // 2048 fragments: [nt_l:4][ks:8][lane:64]
        int nt_l = fi >> 9;
        int rem  = fi & 511;
        int ks   = rem >> 6;
        int lf   = rem & 63;
        int q    = lf >> 4;
        int nl   = lf & 15;
        int code = nt_l * 16 + nl;
        int kb   = ks * 32 + q * 8;
        bf16x8 hh, ll;
#pragma unroll
        for (int j = 0; j < 8; ++j) {
            float v = tile[code][kb + j];
            short h = f2bf(v);
            hh[j] = h;
            ll[j] = f2bf(v - bf2f(h));
        }
        size_t off = ((((size_t)s * 64 + (c0 >> 4) + nt_l) * 8 + ks) * 64 + lf) * 8;
        *(bf16x8*)&chF[off] = hh;
        *(bf16x8*)&clF[off] = ll;
    }
}

// ---------------- init used tail of d_out ----------------
__global__ void init_used_kernel(const int* __restrict__ cbu, float* __restrict__ used) {
    int i = blockIdx.x * 256 + threadIdx.x;
    if (i < NSTAGES * NCODES) used[i] = (float)cbu[i];
}

// ---------------- main fused RVQ (MFMA) ----------------
// block 256 = 4 waves; 64 rows/block; wave w handles codes [w*256, w*256+256)
__global__ __launch_bounds__(256, 2) void rvq_kernel(const float* __restrict__ input,
                                                     const float* __restrict__ cb,
                                                     const short* __restrict__ chF,
                                                     const short* __restrict__ clF,
                                                     const float* __restrict__ cn,
                                                     const float* __restrict__ noise,
                                                     const int* __restrict__ cbu,
                                                     const int* __restrict__ tmp,
                                                     float* __restrict__ out,
                                                     float* __restrict__ used) {
    __shared__ __align__(16) short rhF[4 * 8 * 64 * 8];   // 32 KB  A-frag rh
    __shared__ __align__(16) short rlF[4 * 8 * 64 * 8];   // 32 KB  A-frag rl
    __shared__ float cnS[NCODES];                         // 4 KB
    __shared__ unsigned long long bestkey[TM];
    __shared__ float pr[256], pn[256], scl[TM];

    int t    = threadIdx.x;
    int w    = t >> 6;
    int lane = t & 63;
    int row0 = blockIdx.x * TM;
    int row  = t >> 2;          // update/epilogue mapping: 4 threads per row
    int q4   = t & 3;
    const float* inp = input + (size_t)row0 * DIM;

    // ---- initial: input -> rh/rl A-fragments ----
    {
        const float4* ip4 = (const float4*)(inp + row * DIM + q4 * 64);
#pragma unroll
        for (int a = 0; a < 2; ++a) {
            int ks = q4 * 2 + a;
#pragma unroll
            for (int b = 0; b < 4; ++b) {
                float4 v0 = ip4[a * 8 + b * 2];
                float4 v1 = ip4[a * 8 + b * 2 + 1];
                float v[8] = {v0.x, v0.y, v0.z, v0.w, v1.x, v1.y, v1.z, v1.w};
                bf16x8 hh, ll;
#pragma unroll
                for (int j = 0; j < 8; ++j) {
                    short h = f2bf(v[j]);
                    hh[j] = h;
                    ll[j] = f2bf(v[j] - bf2f(h));
                }
                int off = (((row >> 4) * 8 + ks) * 64 + b * 16 + (row & 15)) * 8;
                *(bf16x8*)&rhF[off] = hh;
                *(bf16x8*)&rlF[off] = ll;
            }
        }
    }
    if (t < TM) bestkey[t] = ~0ULL;

#pragma unroll 1
    for (int s = 0; s < NSTAGES; ++s) {
        for (int i = t; i < NCODES; i += 256) cnS[i] = cn[(size_t)s * NCODES + i];
        __syncthreads();

        unsigned long long mk[16];
#pragma unroll
        for (int i = 0; i < 16; ++i) mk[i] = ~0ULL;

        const short* chW = chF + ((((size_t)s * 64 + w * 16) * 8) * 64 + lane) * 8;
        const short* clW = clF + ((((size_t)s * 64 + w * 16) * 8) * 64 + lane) * 8;

#pragma unroll 1
        for (int cc = 0; cc < 4; ++cc) {
            f32x4 acc[4][4];
#pragma unroll
            for (int mt = 0; mt < 4; ++mt)
#pragma unroll
                for (int nn = 0; nn < 4; ++nn) acc[mt][nn] = (f32x4){0.f, 0.f, 0.f, 0.f};

#pragma unroll 1
            for (int ks = 0; ks < 8; ++ks) {
                bf16x8 Bh[4], Bl[4], Ah[4], Al[4];
#pragma unroll
                for (int nn = 0; nn < 4; ++nn) {
                    size_t off = (size_t)cc * 16384 + (size_t)nn * 4096 + (size_t)ks * 512;
                    Bh[nn] = *(const bf16x8*)&chW[off];
                    Bl[nn] = *(const bf16x8*)&clW[off];
                }
#pragma unroll
                for (int mt = 0; mt < 4; ++mt) {
                    int offA = ((mt * 8 + ks) * 64 + lane) * 8;
                    Ah[mt] = *(const bf16x8*)&rhF[offA];
                    Al[mt] = *(const bf16x8*)&rlF[offA];
                }
#pragma unroll
                for (int mt = 0; mt < 4; ++mt)
#pragma unroll
                    for (int nn = 0; nn < 4; ++nn) {
                        acc[mt][nn] = __builtin_amdgcn_mfma_f32_16x16x32_bf16(Al[mt], Bh[nn], acc[mt][nn], 0, 0, 0);
                        acc[mt][nn] = __builtin_amdgcn_mfma_f32_16x16x32_bf16(Ah[mt], Bl[nn], acc[mt][nn], 0, 0, 0);
                        acc[mt][nn] = __builtin_amdgcn_mfma_f32_16x16x32_bf16(Ah[mt], Bh[nn], acc[mt][nn], 0, 0, 0);
                    }
            }
            // fold scores into running per-(row,colgroup) min
            int code0 = w * 256 + cc * 64 + (lane & 15);
#pragma unroll
            for (int mt = 0; mt < 4; ++mt)
#pragma unroll
                for (int nn = 0; nn < 4; ++nn) {
                    int code = code0 + nn * 16;
                    float cno = cnS[code];
#pragma unroll
                    for (int r = 0; r < 4; ++r) {
                        float sc = cno - 2.0f * acc[mt][nn][r];
                        unsigned long long key = ((unsigned long long)fkey(sc) << 32) | (unsigned)code;
                        int mi = mt * 4 + r;
                        if (key < mk[mi]) mk[mi] = key;
                    }
                }
        }
        // reduce across the 16 lanes of each column group
#pragma unroll
        for (int d = 1; d < 16; d <<= 1)
#pragma unroll
            for (int i = 0; i < 16; ++i) {
                unsigned long long o = __shfl_xor(mk[i], d);
                if (o < mk[i]) mk[i] = o;
            }
        if ((lane & 15) == 0) {
#pragma unroll
            for (int mt = 0; mt < 4; ++mt)
#pragma unroll
                for (int r = 0; r < 4; ++r)
                    atomicMin(&bestkey[mt * 16 + (lane >> 4) * 4 + r], mk[mt * 4 + r]);
        }
        __syncthreads();

        // ---- residual update: res = (rh+rl) - cb[idx], re-split ----
        {
            int idx = (int)(bestkey[row] & 0xffffffffu);
            const float4* cp = (const float4*)(cb + ((size_t)s * NCODES + idx) * DIM + q4 * 64);
#pragma unroll
            for (int a = 0; a < 2; ++a) {
                int ks = q4 * 2 + a;
#pragma unroll
                for (int b = 0; b < 4; ++b) {
                    int off = (((row >> 4) * 8 + ks) * 64 + b * 16 + (row & 15)) * 8;
                    bf16x8 hh = *(bf16x8*)&rhF[off];
                    bf16x8 ll = *(bf16x8*)&rlF[off];
                    float4 c0 = cp[a * 8 + b * 2];
                    float4 c1 = cp[a * 8 + b * 2 + 1];
                    float cv[8] = {c0.x, c0.y, c0.z, c0.w, c1.x, c1.y, c1.z, c1.w};
#pragma unroll
                    for (int j = 0; j < 8; ++j) {
                        float v = bf2f(hh[j]) + bf2f(ll[j]) - cv[j];
                        short h = f2bf(v);
                        hh[j] = h;
                        ll[j] = f2bf(v - bf2f(h));
                    }
                    *(bf16x8*)&rhF[off] = hh;
                    *(bf16x8*)&rlF[off] = ll;
                }
            }
            if (t < TM) {
                int gi = (s << 10) + (int)(bestkey[t] & 0xffffffffu);
                used[gi] = (float)cbu[gi] + 1.0f;
            }
        }
        __syncthreads();
        if (t < TM) bestkey[t] = ~0ULL;
    }

    // ---- epilogue ----
    float sr = 0.f, sn = 0.f;
    {
        const float4* np4 = (const float4*)(noise + (size_t)(row0 + row) * DIM + q4 * 64);
#pragma unroll
        for (int a = 0; a < 2; ++a) {
            int ks = q4 * 2 + a;
#pragma unroll
            for (int b = 0; b < 4; ++b) {
                int off = (((row >> 4) * 8 + ks) * 64 + b * 16 + (row & 15)) * 8;
                bf16x8 hh = *(bf16x8*)&rhF[off];
                bf16x8 ll = *(bf16x8*)&rlF[off];
#pragma unroll
                for (int j = 0; j < 8; ++j) {
                    float v = bf2f(hh[j]) + bf2f(ll[j]);
                    sr += v * v;
                }
            }
        }
#pragma unroll
        for (int i = 0; i < 16; ++i) {
            float4 nv = np4[i];
            sn += nv.x*nv.x + nv.y*nv.y + nv.z*nv.z + nv.w*nv.w;
        }
    }
    pr[t] = sr; pn[t] = sn;
    __syncthreads();
    if (t < TM) {
        float rs = pr[4*t] + pr[4*t+1] + pr[4*t+2] + pr[4*t+3];
        float ns = pn[4*t] + pn[4*t+1] + pn[4*t+2] + pn[4*t+3];
        scl[t] = sqrtf(rs) / sqrtf(ns) + EPSV;
    }
    __syncthreads();
    int tm = tmp[0];
    if (tm) {
        const float4* ib = (const float4*)inp;
        const float4* nb = (const float4*)(noise + (size_t)row0 * DIM);
        float4* ob = (float4*)(out + (size_t)row0 * DIM);
#pragma unroll
        for (int i = 0; i < 16; ++i) {
            int e4 = t + 256 * i;
            int r  = e4 >> 6;
            float sc = scl[r];
            float4 iv = ib[e4];
            float4 nv = nb[e4];
            float4 ov;
            ov.x = iv.x + sc * nv.x; ov.y = iv.y + sc * nv.y;
            ov.z = iv.z + sc * nv.z; ov.w = iv.w + sc * nv.w;
            ob[e4] = ov;
        }
    } else {
        float* op = out + (size_t)(row0 + row) * DIM + q4 * 64;
        const float* ipq = inp + row * DIM + q4 * 64;
#pragma unroll
        for (int a = 0; a < 2; ++a) {
            int ks = q4 * 2 + a;
#pragma unroll
            for (int b = 0; b < 4; ++b) {
                int off = (((row >> 4) * 8 + ks) * 64 + b * 16 + (row & 15)) * 8;
                bf16x8 hh = *(bf16x8*)&rhF[off];
                bf16x8 ll = *(bf16x8*)&rlF[off];
#pragma unroll
                for (int j = 0; j < 8; ++j) {
                    int d = a * 32 + b * 8 + j;
                    op[d] = ipq[d] - (bf2f(hh[j]) + bf2f(ll[j]));
                }
            }
        }
    }
}

extern "C" void kernel_launch(void* const* d_in, const int* in_sizes, int n_in,
                              void* d_out, int out_size, void* d_ws, size_t ws_size,
                              hipStream_t stream) {
    const float* input = (const float*)d_in[0];
    const float* cb    = (const float*)d_in[1];
    const float* noise = (const float*)d_in[2];
    const int*   cbu   = (const int*)d_in[3];
    const int*   tm    = (const int*)d_in[4];
    float* out  = (float*)d_out;
    float* used = out + (size_t)NROWS * DIM;

    short* chF = (short*)d_ws;                               // 4 MB
    short* clF = chF + (size_t)NSTAGES * 64 * 8 * 64 * 8;    // 4 MB
    float* cn  = (float*)(clF + (size_t)NSTAGES * 64 * 8 * 64 * 8);  // 32 KB

    prep_kernel<<<NSTAGES * 16, 256, 0, stream>>>(cb, chF, clF, cn);
    init_used_kernel<<<(NSTAGES * NCODES + 255) / 256, 256, 0, stream>>>(cbu, used);
    rvq_kernel<<<NROWS / TM, 256, 0, stream>>>(input, cb, chF, clF, cn, noise, cbu, tm, out, used);
}